// Round 3
// baseline (382.006 us; speedup 1.0000x reference)
//
#include <hip/hip_runtime.h>
#include <hip/hip_bf16.h>

typedef __hip_bfloat16 bf16;
typedef __bf16 v8bf __attribute__((ext_vector_type(8)));
typedef float v4f __attribute__((ext_vector_type(4)));

#define NB 8
#define NC 512
#define NH 64
#define NW 64
#define NHW 4096
#define NI 64

__device__ __forceinline__ float b2f(bf16 x) { return __bfloat162float(x); }
__device__ __forceinline__ bf16  f2b(float x) { return __float2bfloat16(x); }

// ---- prep: vT[b,px,c] = bf16(value[b,c,px])  +  Wb = bf16(Wv)
__global__ __launch_bounds__(256) void prep_kernel(const float* __restrict__ value,
                                                   const float* __restrict__ Wv,
                                                   bf16* __restrict__ vT,
                                                   bf16* __restrict__ Wb) {
  int t = threadIdx.x;
  if (blockIdx.x < 4096) {
    __shared__ float s[64][65];
    int i = blockIdx.x;
    int b = i >> 9, rem = i & 511;
    int c0 = (rem >> 6) * 64, px0 = (rem & 63) * 64;
    int lane = t & 63, row4 = t >> 6;
    const float* vp = value + (size_t)b * NC * NHW;
    for (int r = row4; r < 64; r += 4)
      s[r][lane] = vp[(size_t)(c0 + r) * NHW + px0 + lane];
    __syncthreads();
    bf16* op = vT + (size_t)b * NHW * NC;
    for (int r = row4; r < 64; r += 4)
      op[(size_t)(px0 + r) * NC + c0 + lane] = f2b(s[lane][r]);
  } else {
    size_t idx = (size_t)(blockIdx.x - 4096) * 1024 + t * 4;
    float4 w = *(const float4*)&Wv[idx];
    union { __bf16 h[4]; uint2 u; } pk;
    pk.h[0] = (__bf16)w.x; pk.h[1] = (__bf16)w.y;
    pk.h[2] = (__bf16)w.z; pk.h[3] = (__bf16)w.w;
    *(uint2*)&Wb[idx] = pk.u;
  }
}

// ---- pv GEMM: pv[b,o,px] = bias[o] + sum_c Wb[o,c] * vT[b,px,c]
// 128x128 tile, BK=64, both operands K-contiguous bf16, LDS pitch 72.
__global__ __launch_bounds__(256) void gemm_nt(const bf16* __restrict__ Wb,
                                               const bf16* __restrict__ vT,
                                               const float* __restrict__ bias,
                                               bf16* __restrict__ out) {
  __shared__ __align__(16) __bf16 As[128 * 72];
  __shared__ __align__(16) __bf16 Bs[128 * 72];
  int t = threadIdx.x;
  int b = blockIdx.x >> 5, pxt = blockIdx.x & 31;
  int px0 = pxt * 128, o0 = blockIdx.y * 128;
  int wave = t >> 6, lane = t & 63;
  int wm = (wave >> 1) * 64, wn = (wave & 1) * 64;
  int row16 = lane & 15, quad = lane >> 4;
  v4f acc[4][4] = {};
  const bf16* Bp = vT + ((size_t)b * NHW + px0) * NC;
  for (int k0 = 0; k0 < NC; k0 += 64) {
#pragma unroll
    for (int ii = 0; ii < 4; ++ii) {
      int i = t + ii * 256;
      int m = i >> 3, ch = i & 7;
      *(uint4*)&As[m * 72 + ch * 8] = *(const uint4*)&Wb[(size_t)(o0 + m) * NC + k0 + ch * 8];
      *(uint4*)&Bs[m * 72 + ch * 8] = *(const uint4*)&Bp[(size_t)m * NC + k0 + ch * 8];
    }
    __syncthreads();
#pragma unroll
    for (int ks = 0; ks < 2; ++ks) {
      v8bf af[4], bf[4];
#pragma unroll
      for (int i = 0; i < 4; ++i) {
        af[i] = *(const v8bf*)&As[(wm + i * 16 + row16) * 72 + ks * 32 + quad * 8];
        bf[i] = *(const v8bf*)&Bs[(wn + i * 16 + row16) * 72 + ks * 32 + quad * 8];
      }
#pragma unroll
      for (int mi = 0; mi < 4; ++mi)
#pragma unroll
        for (int ni = 0; ni < 4; ++ni)
          acc[mi][ni] = __builtin_amdgcn_mfma_f32_16x16x32_bf16(af[mi], bf[ni],
                                                                acc[mi][ni], 0, 0, 0);
    }
    __syncthreads();
  }
#pragma unroll
  for (int mi = 0; mi < 4; ++mi)
#pragma unroll
    for (int r = 0; r < 4; ++r) {
      int m = wm + mi * 16 + quad * 4 + r;
      float bi = bias[o0 + m];
      bf16* orow = out + (size_t)(b * NC + o0 + m) * NHW + px0 + wn + row16;
#pragma unroll
      for (int ni = 0; ni < 4; ++ni)
        orow[ni * 16] = f2b(acc[mi][ni][r] + bi);
    }
}

// ---- pq/pk projection: out[b,o,px] = bias + W X, f32 in.
// TM=64, TN=128, 4 waves: wave (wm,wn) = ((wave>>1)*32, (wave&1)*64),
// each wave computes 32x64 via acc[2][4]. grid 512 blocks -> 2 blocks/CU.
__global__ __launch_bounds__(256) void proj64(const float* __restrict__ X0,
                                              const float* __restrict__ W0,
                                              const float* __restrict__ b0,
                                              bf16* __restrict__ o0p,
                                              const float* __restrict__ X1,
                                              const float* __restrict__ W1,
                                              const float* __restrict__ b1,
                                              bf16* __restrict__ o1p) {
  __shared__ __align__(16) __bf16 As[64 * 72];
  __shared__ __align__(16) __bf16 Bs[128 * 72];
  const float* X = (blockIdx.z == 0) ? X0 : X1;
  const float* Wm = (blockIdx.z == 0) ? W0 : W1;
  const float* bias = (blockIdx.z == 0) ? b0 : b1;
  bf16* out = (blockIdx.z == 0) ? o0p : o1p;
  int t = threadIdx.x;
  int b = blockIdx.x >> 5, nt = blockIdx.x & 31;
  int px0 = nt * 128;
  int wave = t >> 6, lane = t & 63;
  int wm = (wave >> 1) * 32, wn = (wave & 1) * 64;
  int row16 = lane & 15, quad = lane >> 4;
  v4f acc[2][4] = {};
  const float* Xb = X + (size_t)b * NC * NHW + px0;
  int bp = t & 127;            // pixel within tile
  int bch = (t >> 7) * 32;     // channel half
  for (int k0 = 0; k0 < NC; k0 += 64) {
    // stage W rows (64 x 64 f32 -> bf16)
#pragma unroll
    for (int ii = 0; ii < 4; ++ii) {
      int f = t + ii * 256;
      int m = f >> 4, c4 = (f & 15) * 4;
      float4 w = *(const float4*)&Wm[(size_t)m * NC + k0 + c4];
      union { __bf16 h[4]; uint2 u; } pk;
      pk.h[0] = (__bf16)w.x; pk.h[1] = (__bf16)w.y;
      pk.h[2] = (__bf16)w.z; pk.h[3] = (__bf16)w.w;
      *(uint2*)&As[m * 72 + c4] = pk.u;
    }
    // stage X columns (128 px x 64 ch), coalesced across lanes
#pragma unroll
    for (int cc = 0; cc < 32; cc += 8) {
      float r[8];
#pragma unroll
      for (int j = 0; j < 8; ++j)
        r[j] = Xb[(size_t)(k0 + bch + cc + j) * NHW + bp];
      union { __bf16 h[8]; uint4 u; } pk;
#pragma unroll
      for (int j = 0; j < 8; ++j) pk.h[j] = (__bf16)r[j];
      *(uint4*)&Bs[bp * 72 + bch + cc] = pk.u;
    }
    __syncthreads();
#pragma unroll
    for (int ks = 0; ks < 2; ++ks) {
      v8bf af[2], bf[4];
#pragma unroll
      for (int i = 0; i < 2; ++i)
        af[i] = *(const v8bf*)&As[(wm + i * 16 + row16) * 72 + ks * 32 + quad * 8];
#pragma unroll
      for (int i = 0; i < 4; ++i)
        bf[i] = *(const v8bf*)&Bs[(wn + i * 16 + row16) * 72 + ks * 32 + quad * 8];
#pragma unroll
      for (int mi = 0; mi < 2; ++mi)
#pragma unroll
        for (int ni = 0; ni < 4; ++ni)
          acc[mi][ni] = __builtin_amdgcn_mfma_f32_16x16x32_bf16(af[mi], bf[ni],
                                                                acc[mi][ni], 0, 0, 0);
    }
    __syncthreads();
  }
#pragma unroll
  for (int mi = 0; mi < 2; ++mi)
#pragma unroll
    for (int r = 0; r < 4; ++r) {
      int m = wm + mi * 16 + quad * 4 + r;
      float bi = bias[m];
      bf16* orow = out + (size_t)(b * NI + m) * NHW + px0 + wn + row16;
#pragma unroll
      for (int ni = 0; ni < 4; ++ni)
        orow[ni * 16] = f2b(acc[mi][ni][r] + bi);
    }
}

// ---- score (VALU): writes att[((b*64+h)*64+w)*128 + (g | 64+f)]  (f32)
__device__ __forceinline__ void tile_mac(const float (*As)[68], const float (*Bs)[68],
                                         float acc[4][4], int tc, int tr) {
#pragma unroll 16
  for (int k = 0; k < 64; ++k) {
    float a0 = As[k][tc], a1 = As[k][tc + 1], a2 = As[k][tc + 2], a3 = As[k][tc + 3];
    float b0 = Bs[k][tr], b1 = Bs[k][tr + 1], b2 = Bs[k][tr + 2], b3 = Bs[k][tr + 3];
    acc[0][0] += a0 * b0; acc[0][1] += a0 * b1; acc[0][2] += a0 * b2; acc[0][3] += a0 * b3;
    acc[1][0] += a1 * b0; acc[1][1] += a1 * b1; acc[1][2] += a1 * b2; acc[1][3] += a1 * b3;
    acc[2][0] += a2 * b0; acc[2][1] += a2 * b1; acc[2][2] += a2 * b2; acc[2][3] += a2 * b3;
    acc[3][0] += a3 * b0; acc[3][1] += a3 * b1; acc[3][2] += a3 * b2; acc[3][3] += a3 * b3;
  }
}

__global__ __launch_bounds__(256) void score_kernel(const bf16* __restrict__ pq,
                                                    const bf16* __restrict__ pk,
                                                    float* __restrict__ att) {
  __shared__ float As[64][68];
  __shared__ float Bs[64][68];
  int t = threadIdx.x, lane = t & 63, row4 = t >> 6;
  int b = blockIdx.x >> 6, q = blockIdx.x & 63;
  bool isH = (blockIdx.y == 0);
  const bf16* pqb = pq + (size_t)b * NI * NHW;
  const bf16* pkb = pk + (size_t)b * NI * NHW;
  for (int o = row4; o < 64; o += 4) {
    size_t base = (size_t)o * NHW;
    if (isH) {
      As[o][lane] = b2f(pqb[base + (size_t)lane * NW + q]);
      Bs[o][lane] = b2f(pkb[base + (size_t)lane * NW + q]);
    } else {
      As[o][lane] = b2f(pqb[base + (size_t)q * NW + lane]);
      Bs[o][lane] = b2f(pkb[base + (size_t)q * NW + lane]);
    }
  }
  __syncthreads();
  int tc = (t & 15) * 4, tr = (t >> 4) * 4;
  float acc[4][4] = {};
  tile_mac(As, Bs, acc, tc, tr);
#pragma unroll
  for (int i = 0; i < 4; ++i)
#pragma unroll
    for (int j = 0; j < 4; ++j) {
      if (isH) {
        int h = tc + i, g = tr + j;
        float v = (h == g) ? -1e30f : acc[i][j];
        att[((size_t)(b * 64 + h) * 64 + q) * 128 + g] = v;
      } else {
        int w = tc + i, f = tr + j;
        att[((size_t)(b * 64 + q) * 64 + w) * 128 + 64 + f] = acc[i][j];
      }
    }
}

// ---- softmax: reads f32 row (512 B), writes bf16 probs IN-PLACE into the
// first 256 B of the same row (row stride stays 512 B = 256 bf16 elements).
__global__ __launch_bounds__(256) void softmax_kernel(float* __restrict__ att) {
  int wave = threadIdx.x >> 6, lane = threadIdx.x & 63;
  int p = blockIdx.x * 4 + wave;
  float* row = att + (size_t)p * 128;
  float v0 = row[lane], v1 = row[lane + 64];
  float m = fmaxf(v0, v1);
#pragma unroll
  for (int off = 32; off; off >>= 1) m = fmaxf(m, __shfl_xor(m, off));
  float e0 = __expf(v0 - m), e1 = __expf(v1 - m);
  float s = e0 + e1;
#pragma unroll
  for (int off = 32; off; off >>= 1) s += __shfl_xor(s, off);
  float inv = 1.0f / s;
  bf16* rb = (bf16*)row;
  rb[lane] = f2b(e0 * inv);
  rb[lane + 64] = f2b(e1 * inv);
}

__global__ __launch_bounds__(256) void transpose_kernel(const bf16* __restrict__ in,
                                                        bf16* __restrict__ out) {
  __shared__ float s[64][65];
  int lane = threadIdx.x & 63, row4 = threadIdx.x >> 6;
  const bf16* ip = in + (size_t)blockIdx.x * 4096;
  bf16* op = out + (size_t)blockIdx.x * 4096;
  for (int r = row4; r < 64; r += 4) s[r][lane] = b2f(ip[r * 64 + lane]);
  __syncthreads();
  for (int r = row4; r < 64; r += 4) op[r * 64 + lane] = f2b(s[lane][r]);
}

// ---- MFMA apply, c-tile = 128 (grid y = 4). Both modes write bf16 terms:
// mode 0: t1[b,c,w=q,h] = sum_g pvT[b,c,q,g]*attH[b,h,q,g]
// mode 1: t2[b,c,h=q,w] = sum_f pv[b,c,q,f]*attW[b,q,w,f]
//   (mode 1 writes IN-PLACE over pv: each block reads exactly the pv region
//    it overwrites; reads drain into LDS before __syncthreads, stores after.)
// attb: bf16 probs, row stride 256 elements; [0..64)=g-half, [64..128)=f-half.
__global__ __launch_bounds__(256) void apply_mfma(const bf16* pva,
                                                  const bf16* __restrict__ attb,
                                                  bf16* outp, int mode, int strided) {
  __shared__ __align__(16) __bf16 As[128 * 72];
  __shared__ __align__(16) __bf16 Bs[64 * 72];
  int t = threadIdx.x;
  int b = blockIdx.x >> 6, q = blockIdx.x & 63;
  int c0 = blockIdx.y * 128;
  int wave = t >> 6, lane = t & 63;
  int row16 = lane & 15, quad = lane >> 4;
  // stage A (128 rows of pv or pvT, bf16, k-contiguous)
#pragma unroll
  for (int ii = 0; ii < 4; ++ii) {
    int i = t + ii * 256;
    int m = i >> 3, ch = i & 7;
    if (!strided) {
      *(uint4*)&As[m * 72 + ch * 8] =
          *(const uint4*)&pva[((size_t)(b * NC + c0 + m) * 64 + q) * 64 + ch * 8];
    } else {  // compact mode0: pv[b,c,g,q] stride-64 scalar loads
      union { __bf16 h[8]; uint4 u; } pk;
#pragma unroll
      for (int j = 0; j < 8; ++j)
        pk.h[j] = (__bf16)b2f(pva[(size_t)(b * NC + c0 + m) * 4096 +
                                  (size_t)(ch * 8 + j) * 64 + q]);
      *(uint4*)&As[m * 72 + ch * 8] = pk.u;
    }
  }
  // stage B (att rows, already bf16 — straight uint4 copies)
#pragma unroll
  for (int ii = 0; ii < 2; ++ii) {
    int i = t + ii * 256;
    int n = i >> 3, ch = i & 7;
    const bf16* src = (mode == 0)
        ? &attb[((size_t)(b * 64 + n) * 64 + q) * 256 + ch * 8]
        : &attb[((size_t)(b * 64 + q) * 64 + n) * 256 + 64 + ch * 8];
    *(uint4*)&Bs[n * 72 + ch * 8] = *(const uint4*)src;
  }
  __syncthreads();
  v4f acc[2][4] = {};
#pragma unroll
  for (int ks = 0; ks < 2; ++ks) {
    v8bf af[2], bfr[4];
#pragma unroll
    for (int mi = 0; mi < 2; ++mi)
      af[mi] = *(const v8bf*)&As[(wave * 32 + mi * 16 + row16) * 72 + ks * 32 + quad * 8];
#pragma unroll
    for (int ni = 0; ni < 4; ++ni)
      bfr[ni] = *(const v8bf*)&Bs[(ni * 16 + row16) * 72 + ks * 32 + quad * 8];
#pragma unroll
    for (int mi = 0; mi < 2; ++mi)
#pragma unroll
      for (int ni = 0; ni < 4; ++ni)
        acc[mi][ni] = __builtin_amdgcn_mfma_f32_16x16x32_bf16(af[mi], bfr[ni],
                                                              acc[mi][ni], 0, 0, 0);
  }
#pragma unroll
  for (int mi = 0; mi < 2; ++mi)
#pragma unroll
    for (int ni = 0; ni < 4; ++ni)
#pragma unroll
      for (int r = 0; r < 4; ++r) {
        int c = c0 + wave * 32 + mi * 16 + quad * 4 + r;
        int hw = row16 + ni * 16;
        outp[((size_t)(b * NC + c) * 64 + q) * 64 + hw] = f2b(acc[mi][ni][r]);
      }
}

// ---- combine: out[b,c,h,w] = gamma*(t1[b,c,w,h] + t2[b,c,h,w]) + value[b,c,h,w]
// t1 transposed through LDS (proven transpose pattern); everything coalesced.
__global__ __launch_bounds__(256) void combine_kernel(const bf16* __restrict__ t1,
                                                      const bf16* t2,
                                                      const float* __restrict__ value,
                                                      const float* __restrict__ gamma,
                                                      float* __restrict__ out) {
  __shared__ float s[64][65];
  int lane = threadIdx.x & 63, row4 = threadIdx.x >> 6;
  size_t bc = blockIdx.x;
  const bf16* t1p = t1 + bc * 4096;
  for (int r = row4; r < 64; r += 4) s[r][lane] = b2f(t1p[r * 64 + lane]);
  __syncthreads();
  float g = gamma[0];
  const bf16* t2p = t2 + bc * 4096;
  const float* vp = value + bc * 4096;
  float* op = out + bc * 4096;
  for (int r = row4; r < 64; r += 4)
    op[r * 64 + lane] = g * (s[lane][r] + b2f(t2p[r * 64 + lane])) + vp[r * 64 + lane];
}

extern "C" void kernel_launch(void* const* d_in, const int* in_sizes, int n_in,
                              void* d_out, int out_size, void* d_ws, size_t ws_size,
                              hipStream_t stream) {
  const float* query = (const float*)d_in[0];
  const float* key_t = (const float*)d_in[1];
  const float* value = (const float*)d_in[2];
  const float* Wq    = (const float*)d_in[3];
  const float* bq    = (const float*)d_in[4];
  const float* Wk    = (const float*)d_in[5];
  const float* bk    = (const float*)d_in[6];
  const float* Wv    = (const float*)d_in[7];
  const float* bv    = (const float*)d_in[8];
  const float* gamma = (const float*)d_in[9];
  float* out = (float*)d_out;

  // ws (MiB): pq@0(4) pk@4(4) att@8(16,f32; bf16 probs re-packed in-place)
  //           pv@24(32) [full: pvT@56(32) vSLOT@88(32)] [compact: vSLOT@56(32)].
  //           vT lives in vSLOT until gemm_nt completes, then t1 reuses it.
  //           t2 is written IN-PLACE over pv by apply mode 1.
  //           Wb (0.5 MiB) borrows the pq slot. full=120 MiB, compact=88 MiB.
  char* ws = (char*)d_ws;
  bool full = ws_size >= (120ull << 20);
  bf16*  pq  = (bf16*)(ws);
  bf16*  Wb  = (bf16*)(ws);                      // dead before pq is written
  bf16*  pk  = (bf16*)(ws + (4ull << 20));
  float* att = (float*)(ws + (8ull << 20));
  bf16*  attb = (bf16*)att;                      // bf16 probs, row stride 256
  bf16*  pv  = (bf16*)(ws + (24ull << 20));
  bf16*  pvT = (bf16*)(ws + (56ull << 20));
  bf16*  vT  = (bf16*)(ws + ((full ? 88ull : 56ull) << 20));
  bf16*  t1  = vT;                               // reuses slot after vT dies
  bf16*  t2  = pv;                               // in-place over pv (mode 1)

  dim3 blk(256);
  prep_kernel<<<4096 + 256, blk, 0, stream>>>(value, Wv, vT, Wb);
  gemm_nt<<<dim3(NB * 32, 4), blk, 0, stream>>>(Wb, vT, bv, pv);
  if (full) transpose_kernel<<<NB * NC, blk, 0, stream>>>(pv, pvT);
  proj64<<<dim3(NB * 32, 1, 2), blk, 0, stream>>>(
      query, Wq, bq, pq, key_t, Wk, bk, pk);
  score_kernel<<<dim3(NB * 64, 2), blk, 0, stream>>>(pq, pk, att);
  softmax_kernel<<<NB * NHW / 4, blk, 0, stream>>>(att);
  apply_mfma<<<dim3(NB * 64, 4), blk, 0, stream>>>(
      full ? pvT : pv, attb, t1, 0, full ? 0 : 1);
  apply_mfma<<<dim3(NB * 64, 4), blk, 0, stream>>>(pv, attb, t2, 1, 0);
  combine_kernel<<<NB * NC, blk, 0, stream>>>(t1, t2, value, gamma, out);
}

// Round 4
// 365.255 us; speedup vs baseline: 1.0459x; 1.0459x over previous
//
#include <hip/hip_runtime.h>
#include <hip/hip_bf16.h>

typedef __hip_bfloat16 bf16;
typedef __bf16 v8bf __attribute__((ext_vector_type(8)));
typedef float v4f __attribute__((ext_vector_type(4)));

#define NB 8
#define NC 512
#define NH 64
#define NW 64
#define NHW 4096
#define NI 64

__device__ __forceinline__ float b2f(bf16 x) { return __bfloat162float(x); }
__device__ __forceinline__ bf16  f2b(float x) { return __float2bfloat16(x); }

// ---- prep: vT[b,px,c] = bf16(value[b,c,px])  +  Wb = bf16(Wv)
__global__ __launch_bounds__(256) void prep_kernel(const float* __restrict__ value,
                                                   const float* __restrict__ Wv,
                                                   bf16* __restrict__ vT,
                                                   bf16* __restrict__ Wb) {
  int t = threadIdx.x;
  if (blockIdx.x < 4096) {
    __shared__ float s[64][65];
    int i = blockIdx.x;
    int b = i >> 9, rem = i & 511;
    int c0 = (rem >> 6) * 64, px0 = (rem & 63) * 64;
    int lane = t & 63, row4 = t >> 6;
    const float* vp = value + (size_t)b * NC * NHW;
    for (int r = row4; r < 64; r += 4)
      s[r][lane] = vp[(size_t)(c0 + r) * NHW + px0 + lane];
    __syncthreads();
    bf16* op = vT + (size_t)b * NHW * NC;
    for (int r = row4; r < 64; r += 4)
      op[(size_t)(px0 + r) * NC + c0 + lane] = f2b(s[lane][r]);
  } else {
    size_t idx = (size_t)(blockIdx.x - 4096) * 1024 + t * 4;
    float4 w = *(const float4*)&Wv[idx];
    union { __bf16 h[4]; uint2 u; } pk;
    pk.h[0] = (__bf16)w.x; pk.h[1] = (__bf16)w.y;
    pk.h[2] = (__bf16)w.z; pk.h[3] = (__bf16)w.w;
    *(uint2*)&Wb[idx] = pk.u;
  }
}

// ---- pv GEMM: pv[b,o,px] = bias[o] + sum_c Wb[o,c] * vT[b,px,c]
// 128x128 tile, BK=64, both operands K-contiguous bf16, LDS pitch 72.
__global__ __launch_bounds__(256) void gemm_nt(const bf16* __restrict__ Wb,
                                               const bf16* __restrict__ vT,
                                               const float* __restrict__ bias,
                                               bf16* __restrict__ out) {
  __shared__ __align__(16) __bf16 As[128 * 72];
  __shared__ __align__(16) __bf16 Bs[128 * 72];
  int t = threadIdx.x;
  int b = blockIdx.x >> 5, pxt = blockIdx.x & 31;
  int px0 = pxt * 128, o0 = blockIdx.y * 128;
  int wave = t >> 6, lane = t & 63;
  int wm = (wave >> 1) * 64, wn = (wave & 1) * 64;
  int row16 = lane & 15, quad = lane >> 4;
  v4f acc[4][4] = {};
  const bf16* Bp = vT + ((size_t)b * NHW + px0) * NC;
  for (int k0 = 0; k0 < NC; k0 += 64) {
#pragma unroll
    for (int ii = 0; ii < 4; ++ii) {
      int i = t + ii * 256;
      int m = i >> 3, ch = i & 7;
      *(uint4*)&As[m * 72 + ch * 8] = *(const uint4*)&Wb[(size_t)(o0 + m) * NC + k0 + ch * 8];
      *(uint4*)&Bs[m * 72 + ch * 8] = *(const uint4*)&Bp[(size_t)m * NC + k0 + ch * 8];
    }
    __syncthreads();
#pragma unroll
    for (int ks = 0; ks < 2; ++ks) {
      v8bf af[4], bf[4];
#pragma unroll
      for (int i = 0; i < 4; ++i) {
        af[i] = *(const v8bf*)&As[(wm + i * 16 + row16) * 72 + ks * 32 + quad * 8];
        bf[i] = *(const v8bf*)&Bs[(wn + i * 16 + row16) * 72 + ks * 32 + quad * 8];
      }
#pragma unroll
      for (int mi = 0; mi < 4; ++mi)
#pragma unroll
        for (int ni = 0; ni < 4; ++ni)
          acc[mi][ni] = __builtin_amdgcn_mfma_f32_16x16x32_bf16(af[mi], bf[ni],
                                                                acc[mi][ni], 0, 0, 0);
    }
    __syncthreads();
  }
#pragma unroll
  for (int mi = 0; mi < 4; ++mi)
#pragma unroll
    for (int r = 0; r < 4; ++r) {
      int m = wm + mi * 16 + quad * 4 + r;
      float bi = bias[o0 + m];
      bf16* orow = out + (size_t)(b * NC + o0 + m) * NHW + px0 + wn + row16;
#pragma unroll
      for (int ni = 0; ni < 4; ++ni)
        orow[ni * 16] = f2b(acc[mi][ni][r] + bi);
    }
}

// ---- pq/pk projection: out[b,o,px] = bias + W X, f32 in.
// TM=64, TN=128, 4 waves, wave (wm,wn)=((wave>>1)*32,(wave&1)*64), acc[2][4].
// B-stage: float4 along px (coalesced), in-LDS transpose via bf16x4
// ds_write_b64 with XOR-swizzled channel offset (spreads 32 lanes over 8
// banks -> 4-way). Fragment reads apply the same XOR (16B-block bijection).
__global__ __launch_bounds__(256) void proj64(const float* __restrict__ X0,
                                              const float* __restrict__ W0,
                                              const float* __restrict__ b0,
                                              bf16* __restrict__ o0p,
                                              const float* __restrict__ X1,
                                              const float* __restrict__ W1,
                                              const float* __restrict__ b1,
                                              bf16* __restrict__ o1p) {
  __shared__ __align__(16) __bf16 As[64 * 72];
  __shared__ __align__(16) __bf16 Bs[128 * 72];
  const float* X = (blockIdx.z == 0) ? X0 : X1;
  const float* Wm = (blockIdx.z == 0) ? W0 : W1;
  const float* bias = (blockIdx.z == 0) ? b0 : b1;
  bf16* out = (blockIdx.z == 0) ? o0p : o1p;
  int t = threadIdx.x;
  int b = blockIdx.x >> 5, nt = blockIdx.x & 31;
  int px0 = nt * 128;
  int wave = t >> 6, lane = t & 63;
  int wm = (wave >> 1) * 32, wn = (wave & 1) * 64;
  int row16 = lane & 15, quad = lane >> 4;
  v4f acc[2][4] = {};
  const float* Xb = X + (size_t)b * NC * NHW + px0;
  for (int k0 = 0; k0 < NC; k0 += 64) {
    // stage W rows (64 x 64 f32 -> bf16), coalesced
#pragma unroll
    for (int ii = 0; ii < 4; ++ii) {
      int f = t + ii * 256;
      int m = f >> 4, c4 = (f & 15) * 4;
      float4 w = *(const float4*)&Wm[(size_t)m * NC + k0 + c4];
      union { __bf16 h[4]; uint2 u; } pk;
      pk.h[0] = (__bf16)w.x; pk.h[1] = (__bf16)w.y;
      pk.h[2] = (__bf16)w.z; pk.h[3] = (__bf16)w.w;
      *(uint2*)&As[m * 72 + c4] = pk.u;
    }
    // stage X tile (128 px x 64 ch): idx=r*256+t -> ch4=(idx>>5)*4,
    // px4=(idx&31)*4. 4 float4 (adjacent channels) -> 4 bf16x4 b64 writes.
#pragma unroll
    for (int r = 0; r < 2; ++r) {
      int idx = r * 256 + t;
      int ch4 = (idx >> 5) * 4, px4 = (idx & 31) * 4;
      float vv[4][4];
#pragma unroll
      for (int j = 0; j < 4; ++j)
        *(float4*)vv[j] = *(const float4*)&Xb[(size_t)(k0 + ch4 + j) * NHW + px4];
#pragma unroll
      for (int i = 0; i < 4; ++i) {
        union { __bf16 h[4]; uint2 u; } pk;
#pragma unroll
        for (int j = 0; j < 4; ++j) pk.h[j] = (__bf16)vv[j][i];
        int px = px4 + i;
        int boff = px * 144 + ((ch4 * 2) ^ (((px >> 2) & 7) << 4));
        *(uint2*)((char*)Bs + boff) = pk.u;
      }
    }
    __syncthreads();
#pragma unroll
    for (int ks = 0; ks < 2; ++ks) {
      v8bf af[2], bf[4];
#pragma unroll
      for (int i = 0; i < 2; ++i)
        af[i] = *(const v8bf*)&As[(wm + i * 16 + row16) * 72 + ks * 32 + quad * 8];
#pragma unroll
      for (int i = 0; i < 4; ++i) {
        int px = wn + i * 16 + row16;
        int boff = px * 144 + ((ks * 64 + quad * 16) ^ (((px >> 2) & 7) << 4));
        bf[i] = *(const v8bf*)((const char*)Bs + boff);
      }
#pragma unroll
      for (int mi = 0; mi < 2; ++mi)
#pragma unroll
        for (int ni = 0; ni < 4; ++ni)
          acc[mi][ni] = __builtin_amdgcn_mfma_f32_16x16x32_bf16(af[mi], bf[ni],
                                                                acc[mi][ni], 0, 0, 0);
    }
    __syncthreads();
  }
#pragma unroll
  for (int mi = 0; mi < 2; ++mi)
#pragma unroll
    for (int r = 0; r < 4; ++r) {
      int m = wm + mi * 16 + quad * 4 + r;
      float bi = bias[m];
      bf16* orow = out + (size_t)(b * NI + m) * NHW + px0 + wn + row16;
#pragma unroll
      for (int ni = 0; ni < 4; ++ni)
        orow[ni * 16] = f2b(acc[mi][ni][r] + bi);
    }
}

// ---- score (VALU): writes att[((b*64+h)*64+w)*128 + (g | 64+f)]  (f32)
__device__ __forceinline__ void tile_mac(const float (*As)[68], const float (*Bs)[68],
                                         float acc[4][4], int tc, int tr) {
#pragma unroll 16
  for (int k = 0; k < 64; ++k) {
    float a0 = As[k][tc], a1 = As[k][tc + 1], a2 = As[k][tc + 2], a3 = As[k][tc + 3];
    float b0 = Bs[k][tr], b1 = Bs[k][tr + 1], b2 = Bs[k][tr + 2], b3 = Bs[k][tr + 3];
    acc[0][0] += a0 * b0; acc[0][1] += a0 * b1; acc[0][2] += a0 * b2; acc[0][3] += a0 * b3;
    acc[1][0] += a1 * b0; acc[1][1] += a1 * b1; acc[1][2] += a1 * b2; acc[1][3] += a1 * b3;
    acc[2][0] += a2 * b0; acc[2][1] += a2 * b1; acc[2][2] += a2 * b2; acc[2][3] += a2 * b3;
    acc[3][0] += a3 * b0; acc[3][1] += a3 * b1; acc[3][2] += a3 * b2; acc[3][3] += a3 * b3;
  }
}

__global__ __launch_bounds__(256) void score_kernel(const bf16* __restrict__ pq,
                                                    const bf16* __restrict__ pk,
                                                    float* __restrict__ att) {
  __shared__ float As[64][68];
  __shared__ float Bs[64][68];
  int t = threadIdx.x, lane = t & 63, row4 = t >> 6;
  int b = blockIdx.x >> 6, q = blockIdx.x & 63;
  bool isH = (blockIdx.y == 0);
  const bf16* pqb = pq + (size_t)b * NI * NHW;
  const bf16* pkb = pk + (size_t)b * NI * NHW;
  for (int o = row4; o < 64; o += 4) {
    size_t base = (size_t)o * NHW;
    if (isH) {
      As[o][lane] = b2f(pqb[base + (size_t)lane * NW + q]);
      Bs[o][lane] = b2f(pkb[base + (size_t)lane * NW + q]);
    } else {
      As[o][lane] = b2f(pqb[base + (size_t)q * NW + lane]);
      Bs[o][lane] = b2f(pkb[base + (size_t)q * NW + lane]);
    }
  }
  __syncthreads();
  int tc = (t & 15) * 4, tr = (t >> 4) * 4;
  float acc[4][4] = {};
  tile_mac(As, Bs, acc, tc, tr);
#pragma unroll
  for (int i = 0; i < 4; ++i)
#pragma unroll
    for (int j = 0; j < 4; ++j) {
      if (isH) {
        int h = tc + i, g = tr + j;
        float v = (h == g) ? -1e30f : acc[i][j];
        att[((size_t)(b * 64 + h) * 64 + q) * 128 + g] = v;
      } else {
        int w = tc + i, f = tr + j;
        att[((size_t)(b * 64 + q) * 64 + w) * 128 + 64 + f] = acc[i][j];
      }
    }
}

// ---- softmax: reads f32 row (512 B), writes bf16 probs IN-PLACE into the
// first 256 B of the same row (row stride stays 512 B = 256 bf16 elements).
__global__ __launch_bounds__(256) void softmax_kernel(float* __restrict__ att) {
  int wave = threadIdx.x >> 6, lane = threadIdx.x & 63;
  int p = blockIdx.x * 4 + wave;
  float* row = att + (size_t)p * 128;
  float v0 = row[lane], v1 = row[lane + 64];
  float m = fmaxf(v0, v1);
#pragma unroll
  for (int off = 32; off; off >>= 1) m = fmaxf(m, __shfl_xor(m, off));
  float e0 = __expf(v0 - m), e1 = __expf(v1 - m);
  float s = e0 + e1;
#pragma unroll
  for (int off = 32; off; off >>= 1) s += __shfl_xor(s, off);
  float inv = 1.0f / s;
  bf16* rb = (bf16*)row;
  rb[lane] = f2b(e0 * inv);
  rb[lane + 64] = f2b(e1 * inv);
}

__global__ __launch_bounds__(256) void transpose_kernel(const bf16* __restrict__ in,
                                                        bf16* __restrict__ out) {
  __shared__ float s[64][65];
  int lane = threadIdx.x & 63, row4 = threadIdx.x >> 6;
  const bf16* ip = in + (size_t)blockIdx.x * 4096;
  bf16* op = out + (size_t)blockIdx.x * 4096;
  for (int r = row4; r < 64; r += 4) s[r][lane] = b2f(ip[r * 64 + lane]);
  __syncthreads();
  for (int r = row4; r < 64; r += 4) op[r * 64 + lane] = f2b(s[lane][r]);
}

// ---- MFMA apply, c-tile = 128 (grid y = 4). Both modes write bf16 terms:
// mode 0: t1[b,c,w=q,h] = sum_g pvT[b,c,q,g]*attH[b,h,q,g]
// mode 1: t2[b,c,h=q,w] = sum_f pv[b,c,q,f]*attW[b,q,w,f]
//   (mode 1 writes IN-PLACE over pv: each block reads exactly the pv region
//    it overwrites; reads drain into LDS before __syncthreads, stores after.)
// attb: bf16 probs, row stride 256 elements; [0..64)=g-half, [64..128)=f-half.
__global__ __launch_bounds__(256) void apply_mfma(const bf16* pva,
                                                  const bf16* __restrict__ attb,
                                                  bf16* outp, int mode, int strided) {
  __shared__ __align__(16) __bf16 As[128 * 72];
  __shared__ __align__(16) __bf16 Bs[64 * 72];
  int t = threadIdx.x;
  int b = blockIdx.x >> 6, q = blockIdx.x & 63;
  int c0 = blockIdx.y * 128;
  int wave = t >> 6, lane = t & 63;
  int row16 = lane & 15, quad = lane >> 4;
  // stage A (128 rows of pv or pvT, bf16, k-contiguous)
#pragma unroll
  for (int ii = 0; ii < 4; ++ii) {
    int i = t + ii * 256;
    int m = i >> 3, ch = i & 7;
    if (!strided) {
      *(uint4*)&As[m * 72 + ch * 8] =
          *(const uint4*)&pva[((size_t)(b * NC + c0 + m) * 64 + q) * 64 + ch * 8];
    } else {  // compact mode0: pv[b,c,g,q] stride-64 scalar loads
      union { __bf16 h[8]; uint4 u; } pk;
#pragma unroll
      for (int j = 0; j < 8; ++j)
        pk.h[j] = (__bf16)b2f(pva[(size_t)(b * NC + c0 + m) * 4096 +
                                  (size_t)(ch * 8 + j) * 64 + q]);
      *(uint4*)&As[m * 72 + ch * 8] = pk.u;
    }
  }
  // stage B (att rows, already bf16 — straight uint4 copies)
#pragma unroll
  for (int ii = 0; ii < 2; ++ii) {
    int i = t + ii * 256;
    int n = i >> 3, ch = i & 7;
    const bf16* src = (mode == 0)
        ? &attb[((size_t)(b * 64 + n) * 64 + q) * 256 + ch * 8]
        : &attb[((size_t)(b * 64 + q) * 64 + n) * 256 + 64 + ch * 8];
    *(uint4*)&Bs[n * 72 + ch * 8] = *(const uint4*)src;
  }
  __syncthreads();
  v4f acc[2][4] = {};
#pragma unroll
  for (int ks = 0; ks < 2; ++ks) {
    v8bf af[2], bfr[4];
#pragma unroll
    for (int mi = 0; mi < 2; ++mi)
      af[mi] = *(const v8bf*)&As[(wave * 32 + mi * 16 + row16) * 72 + ks * 32 + quad * 8];
#pragma unroll
    for (int ni = 0; ni < 4; ++ni)
      bfr[ni] = *(const v8bf*)&Bs[(ni * 16 + row16) * 72 + ks * 32 + quad * 8];
#pragma unroll
    for (int mi = 0; mi < 2; ++mi)
#pragma unroll
      for (int ni = 0; ni < 4; ++ni)
        acc[mi][ni] = __builtin_amdgcn_mfma_f32_16x16x32_bf16(af[mi], bfr[ni],
                                                              acc[mi][ni], 0, 0, 0);
  }
#pragma unroll
  for (int mi = 0; mi < 2; ++mi)
#pragma unroll
    for (int ni = 0; ni < 4; ++ni)
#pragma unroll
      for (int r = 0; r < 4; ++r) {
        int c = c0 + wave * 32 + mi * 16 + quad * 4 + r;
        int hw = row16 + ni * 16;
        outp[((size_t)(b * NC + c) * 64 + q) * 64 + hw] = f2b(acc[mi][ni][r]);
      }
}

// ---- combine: out[b,c,h,w] = gamma*(t1[b,c,w,h] + t2[b,c,h,w]) + value[b,c,h,w]
// t1 transposed through LDS (proven transpose pattern); everything coalesced.
__global__ __launch_bounds__(256) void combine_kernel(const bf16* __restrict__ t1,
                                                      const bf16* t2,
                                                      const float* __restrict__ value,
                                                      const float* __restrict__ gamma,
                                                      float* __restrict__ out) {
  __shared__ float s[64][65];
  int lane = threadIdx.x & 63, row4 = threadIdx.x >> 6;
  size_t bc = blockIdx.x;
  const bf16* t1p = t1 + bc * 4096;
  for (int r = row4; r < 64; r += 4) s[r][lane] = b2f(t1p[r * 64 + lane]);
  __syncthreads();
  float g = gamma[0];
  const bf16* t2p = t2 + bc * 4096;
  const float* vp = value + bc * 4096;
  float* op = out + bc * 4096;
  for (int r = row4; r < 64; r += 4)
    op[r * 64 + lane] = g * (s[lane][r] + b2f(t2p[r * 64 + lane])) + vp[r * 64 + lane];
}

extern "C" void kernel_launch(void* const* d_in, const int* in_sizes, int n_in,
                              void* d_out, int out_size, void* d_ws, size_t ws_size,
                              hipStream_t stream) {
  const float* query = (const float*)d_in[0];
  const float* key_t = (const float*)d_in[1];
  const float* value = (const float*)d_in[2];
  const float* Wq    = (const float*)d_in[3];
  const float* bq    = (const float*)d_in[4];
  const float* Wk    = (const float*)d_in[5];
  const float* bk    = (const float*)d_in[6];
  const float* Wv    = (const float*)d_in[7];
  const float* bv    = (const float*)d_in[8];
  const float* gamma = (const float*)d_in[9];
  float* out = (float*)d_out;

  // ws (MiB): pq@0(4) pk@4(4) att@8(16,f32; bf16 probs re-packed in-place)
  //           pv@24(32) [full: pvT@56(32) vSLOT@88(32)] [compact: vSLOT@56(32)].
  //           vT lives in vSLOT until gemm_nt completes, then t1 reuses it.
  //           t2 is written IN-PLACE over pv by apply mode 1.
  //           Wb (0.5 MiB) borrows the pq slot. full=120 MiB, compact=88 MiB.
  char* ws = (char*)d_ws;
  bool full = ws_size >= (120ull << 20);
  bf16*  pq  = (bf16*)(ws);
  bf16*  Wb  = (bf16*)(ws);                      // dead before pq is written
  bf16*  pk  = (bf16*)(ws + (4ull << 20));
  float* att = (float*)(ws + (8ull << 20));
  bf16*  attb = (bf16*)att;                      // bf16 probs, row stride 256
  bf16*  pv  = (bf16*)(ws + (24ull << 20));
  bf16*  pvT = (bf16*)(ws + (56ull << 20));
  bf16*  vT  = (bf16*)(ws + ((full ? 88ull : 56ull) << 20));
  bf16*  t1  = vT;                               // reuses slot after vT dies
  bf16*  t2  = pv;                               // in-place over pv (mode 1)

  dim3 blk(256);
  prep_kernel<<<4096 + 256, blk, 0, stream>>>(value, Wv, vT, Wb);
  gemm_nt<<<dim3(NB * 32, 4), blk, 0, stream>>>(Wb, vT, bv, pv);
  if (full) transpose_kernel<<<NB * NC, blk, 0, stream>>>(pv, pvT);
  proj64<<<dim3(NB * 32, 1, 2), blk, 0, stream>>>(
      query, Wq, bq, pq, key_t, Wk, bk, pk);
  score_kernel<<<dim3(NB * 64, 2), blk, 0, stream>>>(pq, pk, att);
  softmax_kernel<<<NB * NHW / 4, blk, 0, stream>>>(att);
  apply_mfma<<<dim3(NB * 64, 4), blk, 0, stream>>>(
      full ? pvT : pv, attb, t1, 0, full ? 0 : 1);
  apply_mfma<<<dim3(NB * 64, 4), blk, 0, stream>>>(pv, attb, t2, 1, 0);
  combine_kernel<<<NB * NC, blk, 0, stream>>>(t1, t2, value, gamma, out);
}

// Round 5
// 357.702 us; speedup vs baseline: 1.0679x; 1.0211x over previous
//
#include <hip/hip_runtime.h>
#include <hip/hip_bf16.h>

typedef __hip_bfloat16 bf16;
typedef __bf16 v8bf __attribute__((ext_vector_type(8)));
typedef float v4f __attribute__((ext_vector_type(4)));

#define NB 8
#define NC 512
#define NH 64
#define NW 64
#define NHW 4096
#define NI 64

__device__ __forceinline__ float b2f(bf16 x) { return __bfloat162float(x); }
__device__ __forceinline__ bf16  f2b(float x) { return __float2bfloat16(x); }

// ---- prep: vT[b,px,c] = bf16(value[b,c,px])  +  Wb/Wqb/Wkb = bf16(W*)
__global__ __launch_bounds__(256) void prep_kernel(const float* __restrict__ value,
                                                   const float* __restrict__ Wv,
                                                   const float* __restrict__ Wq,
                                                   const float* __restrict__ Wk,
                                                   bf16* __restrict__ vT,
                                                   bf16* __restrict__ Wb,
                                                   bf16* __restrict__ Wqb,
                                                   bf16* __restrict__ Wkb) {
  int t = threadIdx.x;
  if (blockIdx.x < 4096) {
    __shared__ float s[64][65];
    int i = blockIdx.x;
    int b = i >> 9, rem = i & 511;
    int c0 = (rem >> 6) * 64, px0 = (rem & 63) * 64;
    int lane = t & 63, row4 = t >> 6;
    const float* vp = value + (size_t)b * NC * NHW;
    for (int r = row4; r < 64; r += 4)
      s[r][lane] = vp[(size_t)(c0 + r) * NHW + px0 + lane];
    __syncthreads();
    bf16* op = vT + (size_t)b * NHW * NC;
    for (int r = row4; r < 64; r += 4)
      op[(size_t)(px0 + r) * NC + c0 + lane] = f2b(s[lane][r]);
  } else {
    int wb = blockIdx.x - 4096;
    const float* src; bf16* dst; int lb;
    if (wb < 256)      { src = Wv; dst = Wb;  lb = wb; }
    else if (wb < 288) { src = Wq; dst = Wqb; lb = wb - 256; }
    else               { src = Wk; dst = Wkb; lb = wb - 288; }
    size_t idx = (size_t)lb * 1024 + t * 4;
    float4 w = *(const float4*)&src[idx];
    union { __bf16 h[4]; uint2 u; } pk;
    pk.h[0] = (__bf16)w.x; pk.h[1] = (__bf16)w.y;
    pk.h[2] = (__bf16)w.z; pk.h[3] = (__bf16)w.w;
    *(uint2*)&dst[idx] = pk.u;
  }
}

// ---- pv GEMM: pv[b,o,px] = bias[o] + sum_c Wb[o,c] * vT[b,px,c]
// 128x128 tile, BK=64, both operands K-contiguous bf16, LDS pitch 72.
__global__ __launch_bounds__(256) void gemm_nt(const bf16* __restrict__ Wb,
                                               const bf16* __restrict__ vT,
                                               const float* __restrict__ bias,
                                               bf16* __restrict__ out) {
  __shared__ __align__(16) __bf16 As[128 * 72];
  __shared__ __align__(16) __bf16 Bs[128 * 72];
  int t = threadIdx.x;
  int b = blockIdx.x >> 5, pxt = blockIdx.x & 31;
  int px0 = pxt * 128, o0 = blockIdx.y * 128;
  int wave = t >> 6, lane = t & 63;
  int wm = (wave >> 1) * 64, wn = (wave & 1) * 64;
  int row16 = lane & 15, quad = lane >> 4;
  v4f acc[4][4] = {};
  const bf16* Bp = vT + ((size_t)b * NHW + px0) * NC;
  for (int k0 = 0; k0 < NC; k0 += 64) {
#pragma unroll
    for (int ii = 0; ii < 4; ++ii) {
      int i = t + ii * 256;
      int m = i >> 3, ch = i & 7;
      *(uint4*)&As[m * 72 + ch * 8] = *(const uint4*)&Wb[(size_t)(o0 + m) * NC + k0 + ch * 8];
      *(uint4*)&Bs[m * 72 + ch * 8] = *(const uint4*)&Bp[(size_t)m * NC + k0 + ch * 8];
    }
    __syncthreads();
#pragma unroll
    for (int ks = 0; ks < 2; ++ks) {
      v8bf af[4], bf[4];
#pragma unroll
      for (int i = 0; i < 4; ++i) {
        af[i] = *(const v8bf*)&As[(wm + i * 16 + row16) * 72 + ks * 32 + quad * 8];
        bf[i] = *(const v8bf*)&Bs[(wn + i * 16 + row16) * 72 + ks * 32 + quad * 8];
      }
#pragma unroll
      for (int mi = 0; mi < 4; ++mi)
#pragma unroll
        for (int ni = 0; ni < 4; ++ni)
          acc[mi][ni] = __builtin_amdgcn_mfma_f32_16x16x32_bf16(af[mi], bf[ni],
                                                                acc[mi][ni], 0, 0, 0);
    }
    __syncthreads();
  }
#pragma unroll
  for (int mi = 0; mi < 4; ++mi)
#pragma unroll
    for (int r = 0; r < 4; ++r) {
      int m = wm + mi * 16 + quad * 4 + r;
      float bi = bias[o0 + m];
      bf16* orow = out + (size_t)(b * NC + o0 + m) * NHW + px0 + wn + row16;
#pragma unroll
      for (int ni = 0; ni < 4; ++ni)
        orow[ni * 16] = f2b(acc[mi][ni][r] + bi);
    }
}

// ---- pq/pk projection v3: X staged RAW f32 via global_load_lds (double-
// buffered, counted vmcnt(8), raw s_barrier). Transpose+cvt on the LDS-read
// side. W fragments direct from global bf16 (Wqb/Wkb, L2-resident).
// Per-8-row 64B cyclic rotation baked into the global source address and
// applied on read -> conflict-free stride-512B ds_read_b32.
// TM=64, TN=128, 4 waves: wm=(wave>>1)*32, wn=(wave&1)*64, acc[2][4].
__global__ __launch_bounds__(256) void proj_lds(const float* __restrict__ X0,
                                                const bf16* __restrict__ Wb0,
                                                const float* __restrict__ b0,
                                                bf16* __restrict__ o0p,
                                                const float* __restrict__ X1,
                                                const bf16* __restrict__ Wb1,
                                                const float* __restrict__ b1,
                                                bf16* __restrict__ o1p) {
  __shared__ __align__(16) float Xs[2][64][128];
  const float* X    = (blockIdx.z == 0) ? X0 : X1;
  const bf16*  Wmb  = (blockIdx.z == 0) ? Wb0 : Wb1;
  const float* bias = (blockIdx.z == 0) ? b0 : b1;
  bf16* out         = (blockIdx.z == 0) ? o0p : o1p;
  int t = threadIdx.x;
  int b = blockIdx.x >> 5, nt = blockIdx.x & 31;
  int px0 = nt * 128;
  int wave = t >> 6, lane = t & 63;
  int wm = (wave >> 1) * 32, wn = (wave & 1) * 64;
  int row16 = lane & 15, quad = lane >> 4;
  const float* Xb = X + (size_t)b * NC * NHW + px0;
  int lhalf = lane >> 5;          // which of the 2 ch-rows this lane covers
  int lcol  = (lane & 31) << 4;   // byte col within dest row
  v4f acc[2][4] = {};
  // prologue: stage k=0 into buf 0 (8 global_load_lds_dwordx4 per wave)
#pragma unroll
  for (int i = 0; i < 8; ++i) {
    int c  = (wave << 4) + (i << 1);
    int ch = c + lhalf;
    int pxl = ((lcol - (((ch >> 3) & 7) << 6)) & 511) >> 2;
    const float* g = Xb + (size_t)ch * NHW + pxl;
    __builtin_amdgcn_global_load_lds(
        (const __attribute__((address_space(1))) void*)g,
        (__attribute__((address_space(3))) void*)&Xs[0][c][0], 16, 0, 0);
  }
#pragma unroll
  for (int k = 0; k < 8; ++k) {
    int k0 = k * 64;
    // W fragments for this step, issued BEFORE the prefetch so vmcnt(8)
    // drains them together with the current buffer's stage.
    v8bf af[2][2];
#pragma unroll
    for (int ks = 0; ks < 2; ++ks)
#pragma unroll
      for (int i = 0; i < 2; ++i)
        af[ks][i] = *(const v8bf*)&Wmb[(size_t)(wm + i * 16 + row16) * NC +
                                       k0 + ks * 32 + quad * 8];
    __builtin_amdgcn_sched_barrier(0);
    if (k != 7) {
      int kn = k0 + 64;
#pragma unroll
      for (int i = 0; i < 8; ++i) {
        int c  = (wave << 4) + (i << 1);
        int ch = c + lhalf;
        int pxl = ((lcol - (((ch >> 3) & 7) << 6)) & 511) >> 2;
        const float* g = Xb + (size_t)(kn + ch) * NHW + pxl;
        __builtin_amdgcn_global_load_lds(
            (const __attribute__((address_space(1))) void*)g,
            (__attribute__((address_space(3))) void*)&Xs[(k + 1) & 1][c][0], 16, 0, 0);
      }
      asm volatile("s_waitcnt vmcnt(8)" ::: "memory");
    } else {
      asm volatile("s_waitcnt vmcnt(0)" ::: "memory");
    }
    __builtin_amdgcn_s_barrier();
    const float(*Xc)[128] = Xs[k & 1];
#pragma unroll
    for (int ks = 0; ks < 2; ++ks) {
      int rot = (ks * 4 + quad) << 6;  // byte rotation for this lane's ch rows
      v8bf bfr[4];
#pragma unroll
      for (int i = 0; i < 4; ++i) {
        int px = wn + i * 16 + row16;
        int colb = ((px << 2) + rot) & 511;
        const char* base = (const char*)&Xc[ks * 32 + quad * 8][0] + colb;
        union { __bf16 h[8]; v8bf v; } pk;
#pragma unroll
        for (int j = 0; j < 8; ++j)
          pk.h[j] = (__bf16)(*(const float*)(base + j * 512));
        bfr[i] = pk.v;
      }
#pragma unroll
      for (int mi = 0; mi < 2; ++mi)
#pragma unroll
        for (int ni = 0; ni < 4; ++ni)
          acc[mi][ni] = __builtin_amdgcn_mfma_f32_16x16x32_bf16(af[ks][mi], bfr[ni],
                                                                acc[mi][ni], 0, 0, 0);
    }
    __builtin_amdgcn_s_barrier();
  }
#pragma unroll
  for (int mi = 0; mi < 2; ++mi)
#pragma unroll
    for (int r = 0; r < 4; ++r) {
      int m = wm + mi * 16 + quad * 4 + r;
      float bi = bias[m];
      bf16* orow = out + (size_t)(b * NI + m) * NHW + px0 + wn + row16;
#pragma unroll
      for (int ni = 0; ni < 4; ++ni)
        orow[ni * 16] = f2b(acc[mi][ni][r] + bi);
    }
}

// ---- score (VALU): writes att[((b*64+h)*64+w)*128 + (g | 64+f)]  (f32)
__device__ __forceinline__ void tile_mac(const float (*As)[68], const float (*Bs)[68],
                                         float acc[4][4], int tc, int tr) {
#pragma unroll 16
  for (int k = 0; k < 64; ++k) {
    float a0 = As[k][tc], a1 = As[k][tc + 1], a2 = As[k][tc + 2], a3 = As[k][tc + 3];
    float b0 = Bs[k][tr], b1 = Bs[k][tr + 1], b2 = Bs[k][tr + 2], b3 = Bs[k][tr + 3];
    acc[0][0] += a0 * b0; acc[0][1] += a0 * b1; acc[0][2] += a0 * b2; acc[0][3] += a0 * b3;
    acc[1][0] += a1 * b0; acc[1][1] += a1 * b1; acc[1][2] += a1 * b2; acc[1][3] += a1 * b3;
    acc[2][0] += a2 * b0; acc[2][1] += a2 * b1; acc[2][2] += a2 * b2; acc[2][3] += a2 * b3;
    acc[3][0] += a3 * b0; acc[3][1] += a3 * b1; acc[3][2] += a3 * b2; acc[3][3] += a3 * b3;
  }
}

__global__ __launch_bounds__(256) void score_kernel(const bf16* __restrict__ pq,
                                                    const bf16* __restrict__ pk,
                                                    float* __restrict__ att) {
  __shared__ float As[64][68];
  __shared__ float Bs[64][68];
  int t = threadIdx.x, lane = t & 63, row4 = t >> 6;
  int b = blockIdx.x >> 6, q = blockIdx.x & 63;
  bool isH = (blockIdx.y == 0);
  const bf16* pqb = pq + (size_t)b * NI * NHW;
  const bf16* pkb = pk + (size_t)b * NI * NHW;
  for (int o = row4; o < 64; o += 4) {
    size_t base = (size_t)o * NHW;
    if (isH) {
      As[o][lane] = b2f(pqb[base + (size_t)lane * NW + q]);
      Bs[o][lane] = b2f(pkb[base + (size_t)lane * NW + q]);
    } else {
      As[o][lane] = b2f(pqb[base + (size_t)q * NW + lane]);
      Bs[o][lane] = b2f(pkb[base + (size_t)q * NW + lane]);
    }
  }
  __syncthreads();
  int tc = (t & 15) * 4, tr = (t >> 4) * 4;
  float acc[4][4] = {};
  tile_mac(As, Bs, acc, tc, tr);
#pragma unroll
  for (int i = 0; i < 4; ++i)
#pragma unroll
    for (int j = 0; j < 4; ++j) {
      if (isH) {
        int h = tc + i, g = tr + j;
        float v = (h == g) ? -1e30f : acc[i][j];
        att[((size_t)(b * 64 + h) * 64 + q) * 128 + g] = v;
      } else {
        int w = tc + i, f = tr + j;
        att[((size_t)(b * 64 + q) * 64 + w) * 128 + 64 + f] = acc[i][j];
      }
    }
}

// ---- softmax: reads f32 row (512 B), writes bf16 probs IN-PLACE into the
// first 256 B of the same row (row stride stays 512 B = 256 bf16 elements).
__global__ __launch_bounds__(256) void softmax_kernel(float* __restrict__ att) {
  int wave = threadIdx.x >> 6, lane = threadIdx.x & 63;
  int p = blockIdx.x * 4 + wave;
  float* row = att + (size_t)p * 128;
  float v0 = row[lane], v1 = row[lane + 64];
  float m = fmaxf(v0, v1);
#pragma unroll
  for (int off = 32; off; off >>= 1) m = fmaxf(m, __shfl_xor(m, off));
  float e0 = __expf(v0 - m), e1 = __expf(v1 - m);
  float s = e0 + e1;
#pragma unroll
  for (int off = 32; off; off >>= 1) s += __shfl_xor(s, off);
  float inv = 1.0f / s;
  bf16* rb = (bf16*)row;
  rb[lane] = f2b(e0 * inv);
  rb[lane + 64] = f2b(e1 * inv);
}

__global__ __launch_bounds__(256) void transpose_kernel(const bf16* __restrict__ in,
                                                        bf16* __restrict__ out) {
  __shared__ float s[64][65];
  int lane = threadIdx.x & 63, row4 = threadIdx.x >> 6;
  const bf16* ip = in + (size_t)blockIdx.x * 4096;
  bf16* op = out + (size_t)blockIdx.x * 4096;
  for (int r = row4; r < 64; r += 4) s[r][lane] = b2f(ip[r * 64 + lane]);
  __syncthreads();
  for (int r = row4; r < 64; r += 4) op[r * 64 + lane] = f2b(s[lane][r]);
}

// ---- MFMA apply, c-tile = 128 (grid y = 4). Both modes write bf16 terms:
// mode 0: t1[b,c,w=q,h] = sum_g pvT[b,c,q,g]*attH[b,h,q,g]
// mode 1: t2[b,c,h=q,w] = sum_f pv[b,c,q,f]*attW[b,q,w,f]
//   (mode 1 writes IN-PLACE over pv: each block reads exactly the pv region
//    it overwrites; reads drain into LDS before __syncthreads, stores after.)
// attb: bf16 probs, row stride 256 elements; [0..64)=g-half, [64..128)=f-half.
__global__ __launch_bounds__(256) void apply_mfma(const bf16* pva,
                                                  const bf16* __restrict__ attb,
                                                  bf16* outp, int mode, int strided) {
  __shared__ __align__(16) __bf16 As[128 * 72];
  __shared__ __align__(16) __bf16 Bs[64 * 72];
  int t = threadIdx.x;
  int b = blockIdx.x >> 6, q = blockIdx.x & 63;
  int c0 = blockIdx.y * 128;
  int wave = t >> 6, lane = t & 63;
  int row16 = lane & 15, quad = lane >> 4;
  // stage A (128 rows of pv or pvT, bf16, k-contiguous)
#pragma unroll
  for (int ii = 0; ii < 4; ++ii) {
    int i = t + ii * 256;
    int m = i >> 3, ch = i & 7;
    if (!strided) {
      *(uint4*)&As[m * 72 + ch * 8] =
          *(const uint4*)&pva[((size_t)(b * NC + c0 + m) * 64 + q) * 64 + ch * 8];
    } else {  // compact mode0: pv[b,c,g,q] stride-64 scalar loads
      union { __bf16 h[8]; uint4 u; } pk;
#pragma unroll
      for (int j = 0; j < 8; ++j)
        pk.h[j] = (__bf16)b2f(pva[(size_t)(b * NC + c0 + m) * 4096 +
                                  (size_t)(ch * 8 + j) * 64 + q]);
      *(uint4*)&As[m * 72 + ch * 8] = pk.u;
    }
  }
  // stage B (att rows, already bf16 — straight uint4 copies)
#pragma unroll
  for (int ii = 0; ii < 2; ++ii) {
    int i = t + ii * 256;
    int n = i >> 3, ch = i & 7;
    const bf16* src = (mode == 0)
        ? &attb[((size_t)(b * 64 + n) * 64 + q) * 256 + ch * 8]
        : &attb[((size_t)(b * 64 + q) * 64 + n) * 256 + 64 + ch * 8];
    *(uint4*)&Bs[n * 72 + ch * 8] = *(const uint4*)src;
  }
  __syncthreads();
  v4f acc[2][4] = {};
#pragma unroll
  for (int ks = 0; ks < 2; ++ks) {
    v8bf af[2], bfr[4];
#pragma unroll
    for (int mi = 0; mi < 2; ++mi)
      af[mi] = *(const v8bf*)&As[(wave * 32 + mi * 16 + row16) * 72 + ks * 32 + quad * 8];
#pragma unroll
    for (int ni = 0; ni < 4; ++ni)
      bfr[ni] = *(const v8bf*)&Bs[(ni * 16 + row16) * 72 + ks * 32 + quad * 8];
#pragma unroll
    for (int mi = 0; mi < 2; ++mi)
#pragma unroll
      for (int ni = 0; ni < 4; ++ni)
        acc[mi][ni] = __builtin_amdgcn_mfma_f32_16x16x32_bf16(af[mi], bfr[ni],
                                                              acc[mi][ni], 0, 0, 0);
  }
#pragma unroll
  for (int mi = 0; mi < 2; ++mi)
#pragma unroll
    for (int ni = 0; ni < 4; ++ni)
#pragma unroll
      for (int r = 0; r < 4; ++r) {
        int c = c0 + wave * 32 + mi * 16 + quad * 4 + r;
        int hw = row16 + ni * 16;
        outp[((size_t)(b * NC + c) * 64 + q) * 64 + hw] = f2b(acc[mi][ni][r]);
      }
}

// ---- combine: out[b,c,h,w] = gamma*(t1[b,c,w,h] + t2[b,c,h,w]) + value[b,c,h,w]
__global__ __launch_bounds__(256) void combine_kernel(const bf16* __restrict__ t1,
                                                      const bf16* t2,
                                                      const float* __restrict__ value,
                                                      const float* __restrict__ gamma,
                                                      float* __restrict__ out) {
  __shared__ float s[64][65];
  int lane = threadIdx.x & 63, row4 = threadIdx.x >> 6;
  size_t bc = blockIdx.x;
  const bf16* t1p = t1 + bc * 4096;
  for (int r = row4; r < 64; r += 4) s[r][lane] = b2f(t1p[r * 64 + lane]);
  __syncthreads();
  float g = gamma[0];
  const bf16* t2p = t2 + bc * 4096;
  const float* vp = value + bc * 4096;
  float* op = out + bc * 4096;
  for (int r = row4; r < 64; r += 4)
    op[r * 64 + lane] = g * (s[lane][r] + b2f(t2p[r * 64 + lane])) + vp[r * 64 + lane];
}

extern "C" void kernel_launch(void* const* d_in, const int* in_sizes, int n_in,
                              void* d_out, int out_size, void* d_ws, size_t ws_size,
                              hipStream_t stream) {
  const float* query = (const float*)d_in[0];
  const float* key_t = (const float*)d_in[1];
  const float* value = (const float*)d_in[2];
  const float* Wq    = (const float*)d_in[3];
  const float* bq    = (const float*)d_in[4];
  const float* Wk    = (const float*)d_in[5];
  const float* bk    = (const float*)d_in[6];
  const float* Wv    = (const float*)d_in[7];
  const float* bv    = (const float*)d_in[8];
  const float* gamma = (const float*)d_in[9];
  float* out = (float*)d_out;

  // ws (MiB): pq@0(4) pk@4(4) att@8(16,f32; bf16 probs re-packed in-place;
  //           Wqb/Wkb borrow its first 128 KB until score runs)
  //           pv@24(32) [full: pvT@56(32) vSLOT@88(32)] [compact: vSLOT@56(32)].
  //           vT lives in vSLOT until gemm_nt completes, then t1 reuses it.
  //           t2 is written IN-PLACE over pv by apply mode 1.
  //           Wb (0.5 MiB) borrows the pq slot. full=120 MiB, compact=88 MiB.
  char* ws = (char*)d_ws;
  bool full = ws_size >= (120ull << 20);
  bf16*  pq  = (bf16*)(ws);
  bf16*  Wb  = (bf16*)(ws);                      // dead before pq is written
  bf16*  pk  = (bf16*)(ws + (4ull << 20));
  float* att = (float*)(ws + (8ull << 20));
  bf16*  Wqb = (bf16*)(ws + (8ull << 20));       // dead before att is written
  bf16*  Wkb = Wqb + 64 * 512;
  bf16*  attb = (bf16*)att;                      // bf16 probs, row stride 256
  bf16*  pv  = (bf16*)(ws + (24ull << 20));
  bf16*  pvT = (bf16*)(ws + (56ull << 20));
  bf16*  vT  = (bf16*)(ws + ((full ? 88ull : 56ull) << 20));
  bf16*  t1  = vT;                               // reuses slot after vT dies
  bf16*  t2  = pv;                               // in-place over pv (mode 1)

  dim3 blk(256);
  prep_kernel<<<4096 + 256 + 64, blk, 0, stream>>>(value, Wv, Wq, Wk,
                                                   vT, Wb, Wqb, Wkb);
  gemm_nt<<<dim3(NB * 32, 4), blk, 0, stream>>>(Wb, vT, bv, pv);
  if (full) transpose_kernel<<<NB * NC, blk, 0, stream>>>(pv, pvT);
  proj_lds<<<dim3(NB * 32, 1, 2), blk, 0, stream>>>(
      query, Wqb, bq, pq, key_t, Wkb, bk, pk);
  score_kernel<<<dim3(NB * 64, 2), blk, 0, stream>>>(pq, pk, att);
  softmax_kernel<<<NB * NHW / 4, blk, 0, stream>>>(att);
  apply_mfma<<<dim3(NB * 64, 4), blk, 0, stream>>>(
      full ? pvT : pv, attb, t1, 0, full ? 0 : 1);
  apply_mfma<<<dim3(NB * 64, 4), blk, 0, stream>>>(pv, attb, t2, 1, 0);
  combine_kernel<<<NB * NC, blk, 0, stream>>>(t1, t2, value, gamma, out);
}